// Round 1
// baseline (773.658 us; speedup 1.0000x reference)
//
#include <hip/hip_runtime.h>
#include <hip/hip_bf16.h>
#include <stdint.h>

#define BDIM 4
#define SDIM 1024
#define DDIM 1024
#define HDIM 16
#define DHDIM 64

typedef __bf16 bf16_t;
typedef __bf16 bf16x8 __attribute__((ext_vector_type(8)));
typedef __bf16 bf16x4 __attribute__((ext_vector_type(4)));
typedef float f32x4 __attribute__((ext_vector_type(4)));

// ---------------- conversions ----------------

__global__ __launch_bounds__(256) void convert_x_kernel(const float* __restrict__ X,
                                                        bf16_t* __restrict__ Xb, int n) {
    int i = (blockIdx.x * 256 + threadIdx.x) * 4;
    if (i >= n) return;
    float4 v = *(const float4*)(X + i);
    bf16x4 o;
    o[0] = (bf16_t)v.x; o[1] = (bf16_t)v.y; o[2] = (bf16_t)v.z; o[3] = (bf16_t)v.w;
    *(bf16x4*)(Xb + i) = o;
}

// W[k][n] fp32 -> Wt[n][k] bf16, for 4 weights (z selects)
__global__ __launch_bounds__(256) void transpose_w_kernel(const float* __restrict__ W0,
                                                          const float* __restrict__ W1,
                                                          const float* __restrict__ W2,
                                                          const float* __restrict__ W3,
                                                          bf16_t* __restrict__ Wt) {
    __shared__ float tile[32][33];
    int z = blockIdx.z;
    const float* W = (z == 0) ? W0 : (z == 1) ? W1 : (z == 2) ? W2 : W3;
    bf16_t* dst = Wt + (size_t)z * DDIM * DDIM;
    int bx = blockIdx.x * 32;  // n tile
    int by = blockIdx.y * 32;  // k tile
    int x = threadIdx.x & 31, y0 = threadIdx.x >> 5;
#pragma unroll
    for (int i = 0; i < 4; i++) {
        int y = y0 + i * 8;
        tile[y][x] = W[(size_t)(by + y) * DDIM + bx + x];
    }
    __syncthreads();
#pragma unroll
    for (int i = 0; i < 4; i++) {
        int y = y0 + i * 8;
        dst[(size_t)(bx + y) * DDIM + by + x] = (bf16_t)tile[x][y];
    }
}

// Detect mask element layout: uint8 bools -> bytes at i%4!=0 are often 1;
// int32 -> those bytes are all 0. flag=1 means stride 1 (uint8), else stride 4.
__global__ __launch_bounds__(256) void mask_flag_kernel(const unsigned char* __restrict__ mb,
                                                        int* __restrict__ flag) {
    __shared__ int any;
    if (threadIdx.x == 0) any = 0;
    __syncthreads();
    int loc = 0;
    for (int i = threadIdx.x; i < BDIM * SDIM; i += 256)
        if ((i & 3) && mb[i]) loc = 1;
    if (loc) any = 1;
    __syncthreads();
    if (threadIdx.x == 0) *flag = any ? 1 : 0;
}

// ---------------- GEMM: C[m,n] = sum_k A[m,k] * Bt[n,k] ----------------
// MODE 0: write Q,K,V bf16 [B,H,S,DH] (Q scaled by 0.125), N=3072
// MODE 1: write fp32 C row-major [M,1024]
template <int MODE>
__global__ __launch_bounds__(256) void gemm_bt_kernel(const bf16_t* __restrict__ A,
                                                      const bf16_t* __restrict__ Bt,
                                                      bf16_t* __restrict__ Qo, bf16_t* __restrict__ Ko,
                                                      bf16_t* __restrict__ Vo, float* __restrict__ Co) {
    constexpr int LDT = 40;  // 32 + 8 pad (bank-conflict break), keeps 16B alignment
    __shared__ bf16_t As[128 * LDT];
    __shared__ bf16_t Bs[128 * LDT];
    const int m0 = blockIdx.x * 128;
    const int n0 = blockIdx.y * 128;
    const int t = threadIdx.x;
    const int lane = t & 63, w = t >> 6;
    const int wm = w & 1, wn = w >> 1;
    const int low = lane & 15, quad = lane >> 4;
    f32x4 acc[4][4] = {};

    const int srow = t >> 2, koff = (t & 3) * 8;
    const bf16_t* Ag = A + (size_t)(m0 + srow) * DDIM + koff;
    const bf16_t* Bg = Bt + (size_t)(n0 + srow) * DDIM + koff;

    for (int k0 = 0; k0 < DDIM; k0 += 32) {
        uint4 a0 = *(const uint4*)(Ag + k0);
        uint4 a1 = *(const uint4*)(Ag + (size_t)64 * DDIM + k0);
        uint4 b0 = *(const uint4*)(Bg + k0);
        uint4 b1 = *(const uint4*)(Bg + (size_t)64 * DDIM + k0);
        __syncthreads();
        *(uint4*)(As + srow * LDT + koff) = a0;
        *(uint4*)(As + (srow + 64) * LDT + koff) = a1;
        *(uint4*)(Bs + srow * LDT + koff) = b0;
        *(uint4*)(Bs + (srow + 64) * LDT + koff) = b1;
        __syncthreads();
        bf16x8 af[4], bv[4];
#pragma unroll
        for (int mt = 0; mt < 4; mt++)
            af[mt] = *(const bf16x8*)(As + (wm * 64 + mt * 16 + low) * LDT + quad * 8);
#pragma unroll
        for (int nt = 0; nt < 4; nt++)
            bv[nt] = *(const bf16x8*)(Bs + (wn * 64 + nt * 16 + low) * LDT + quad * 8);
#pragma unroll
        for (int mt = 0; mt < 4; mt++)
#pragma unroll
            for (int nt = 0; nt < 4; nt++)
                acc[mt][nt] = __builtin_amdgcn_mfma_f32_16x16x32_bf16(af[mt], bv[nt], acc[mt][nt], 0, 0, 0);
    }

#pragma unroll
    for (int mt = 0; mt < 4; mt++) {
#pragma unroll
        for (int nt = 0; nt < 4; nt++) {
#pragma unroll
            for (int r = 0; r < 4; r++) {
                int mrow = m0 + wm * 64 + mt * 16 + quad * 4 + r;
                int ncol = n0 + wn * 64 + nt * 16 + low;
                float vv = acc[mt][nt][r];
                if (MODE == 0) {
                    int which = ncol >> 10, nl = ncol & 1023;
                    int h = nl >> 6, dh = nl & 63;
                    int b = mrow >> 10, s = mrow & 1023;
                    size_t idx = ((size_t)(b * HDIM + h) * SDIM + s) * DHDIM + dh;
                    if (which == 0) Qo[idx] = (bf16_t)(vv * 0.125f);
                    else if (which == 1) Ko[idx] = (bf16_t)vv;
                    else Vo[idx] = (bf16_t)vv;
                } else {
                    Co[(size_t)mrow * DDIM + ncol] = vv;
                }
            }
        }
    }
}

// ---------------- fused attention ----------------
// grid: (B*H, S/64); block 256 (4 waves); wave w owns q rows [q0+16w, q0+16w+16)
__global__ __launch_bounds__(256) void attn_kernel(const bf16_t* __restrict__ Q,
                                                   const bf16_t* __restrict__ K,
                                                   const bf16_t* __restrict__ V,
                                                   const float* __restrict__ inter,
                                                   const unsigned char* __restrict__ maskb,
                                                   const int* __restrict__ flagp,
                                                   bf16_t* __restrict__ hid) {
    __shared__ bf16_t Vt[64 * 72];   // V^T tile: [dh][key], padded stride 72
    __shared__ bf16_t P[4][16 * 72]; // per-wave P tile, padded stride 72
    const int bh = blockIdx.x;
    const int b = bh >> 4, h = bh & 15;
    const int q0 = blockIdx.y * 64;
    const int t = threadIdx.x;
    const int w = t >> 6, lane = t & 63;
    const int low = lane & 15, quad = lane >> 4;
    const int mstride = (*flagp) ? 1 : 4;

    const bf16_t* Qb = Q + (size_t)bh * SDIM * DHDIM;
    const bf16_t* Kb = K + (size_t)bh * SDIM * DHDIM;
    const bf16_t* Vb = V + (size_t)bh * SDIM * DHDIM;
    const float* interB = inter + (size_t)b * SDIM * SDIM * HDIM + h;
    const unsigned char* mb = maskb + (size_t)b * SDIM * mstride;

    const int qrow = q0 + w * 16 + low;  // A-operand row (q)
    bf16x8 qf0 = *(const bf16x8*)(Qb + (size_t)qrow * DHDIM + quad * 8);
    bf16x8 qf1 = *(const bf16x8*)(Qb + (size_t)qrow * DHDIM + 32 + quad * 8);

    const int qr = q0 + w * 16 + quad * 4;  // C-layout row base

    float mrow[4], lrow[4];
    f32x4 accO[4] = {};
#pragma unroll
    for (int r = 0; r < 4; r++) { mrow[r] = -3.0e38f; lrow[r] = 0.f; }

    for (int kt = 0; kt < SDIM / 64; kt++) {
        const int kbase = kt * 64;
        __syncthreads();  // prior-iteration Vt/P reads complete
        // stage V^T: 512 chunks of 8 bf16
        {
            int c0 = t, c1 = t + 256;
            int key0 = c0 >> 3, d0 = (c0 & 7) * 8;
            int key1 = c1 >> 3, d1 = (c1 & 7) * 8;
            bf16x8 v0 = *(const bf16x8*)(Vb + (size_t)(kbase + key0) * DHDIM + d0);
            bf16x8 v1 = *(const bf16x8*)(Vb + (size_t)(kbase + key1) * DHDIM + d1);
#pragma unroll
            for (int u = 0; u < 8; u++) Vt[(d0 + u) * 72 + key0] = v0[u];
#pragma unroll
            for (int u = 0; u < 8; u++) Vt[(d1 + u) * 72 + key1] = v1[u];
        }
        // S = Q K^T (Q pre-scaled by 0.125)
        f32x4 sacc[4];
#pragma unroll
        for (int nt = 0; nt < 4; nt++) {
            int krow = kbase + nt * 16 + low;
            bf16x8 kf0 = *(const bf16x8*)(Kb + (size_t)krow * DHDIM + quad * 8);
            bf16x8 kf1 = *(const bf16x8*)(Kb + (size_t)krow * DHDIM + 32 + quad * 8);
            f32x4 z = {};
            z = __builtin_amdgcn_mfma_f32_16x16x32_bf16(qf0, kf0, z, 0, 0, 0);
            z = __builtin_amdgcn_mfma_f32_16x16x32_bf16(qf1, kf1, z, 0, 0, 0);
            sacc[nt] = z;
        }
        __syncthreads();  // Vt ready
        // bias + mask
        float sv[4][4];
#pragma unroll
        for (int nt = 0; nt < 4; nt++) {
            int kk = kbase + nt * 16 + low;
            float pen = mb[kk * mstride] ? 0.f : 1.0e9f;
#pragma unroll
            for (int r = 0; r < 4; r++) {
                float biasv = interB[((size_t)(qr + r) * SDIM + kk) * HDIM];
                sv[nt][r] = sacc[nt][r] + biasv - pen;
            }
        }
        // online softmax update (rows live in a 16-lane quad)
#pragma unroll
        for (int r = 0; r < 4; r++) {
            float vmx = fmaxf(fmaxf(sv[0][r], sv[1][r]), fmaxf(sv[2][r], sv[3][r]));
            vmx = fmaxf(vmx, __shfl_xor(vmx, 1));
            vmx = fmaxf(vmx, __shfl_xor(vmx, 2));
            vmx = fmaxf(vmx, __shfl_xor(vmx, 4));
            vmx = fmaxf(vmx, __shfl_xor(vmx, 8));
            float mn = fmaxf(mrow[r], vmx);
            float alpha = __expf(mrow[r] - mn);
            mrow[r] = mn;
            lrow[r] *= alpha;
#pragma unroll
            for (int nt = 0; nt < 4; nt++) accO[nt][r] *= alpha;
            float rs = 0.f;
#pragma unroll
            for (int nt = 0; nt < 4; nt++) {
                float p = __expf(sv[nt][r] - mn);
                sv[nt][r] = p;
                rs += p;
            }
            rs += __shfl_xor(rs, 1);
            rs += __shfl_xor(rs, 2);
            rs += __shfl_xor(rs, 4);
            rs += __shfl_xor(rs, 8);
            lrow[r] += rs;
        }
        // P (C-layout) -> LDS (A-layout readable)
        bf16_t* Pw = &P[w][0];
#pragma unroll
        for (int nt = 0; nt < 4; nt++)
#pragma unroll
            for (int r = 0; r < 4; r++)
                Pw[(quad * 4 + r) * 72 + nt * 16 + low] = (bf16_t)sv[nt][r];
        __syncthreads();
        // O += P V
#pragma unroll
        for (int step = 0; step < 2; step++) {
            bf16x8 pf = *(const bf16x8*)(Pw + low * 72 + step * 32 + quad * 8);
#pragma unroll
            for (int nt = 0; nt < 4; nt++) {
                bf16x8 vf = *(const bf16x8*)(Vt + (nt * 16 + low) * 72 + step * 32 + quad * 8);
                accO[nt] = __builtin_amdgcn_mfma_f32_16x16x32_bf16(pf, vf, accO[nt], 0, 0, 0);
            }
        }
    }
    // epilogue: hidden[b, q, h*64+dh] bf16
#pragma unroll
    for (int r = 0; r < 4; r++) {
        float inv = 1.f / lrow[r];
#pragma unroll
        for (int nt = 0; nt < 4; nt++) {
            hid[((size_t)b * SDIM + (qr + r)) * DDIM + h * 64 + nt * 16 + low] =
                (bf16_t)(accO[nt][r] * inv);
        }
    }
}

// ---------------- launcher ----------------

extern "C" void kernel_launch(void* const* d_in, const int* in_sizes, int n_in,
                              void* d_out, int out_size, void* d_ws, size_t ws_size,
                              hipStream_t stream) {
    const float* X = (const float*)d_in[0];
    const unsigned char* maskb = (const unsigned char*)d_in[1];
    const float* inter = (const float*)d_in[2];
    const float* WQ = (const float*)d_in[3];
    const float* WK = (const float*)d_in[4];
    const float* WV = (const float*)d_in[5];
    const float* WO = (const float*)d_in[6];
    float* out = (float*)d_out;

    char* ws = (char*)d_ws;
    const size_t MB = 1024 * 1024;
    bf16_t* Xb  = (bf16_t*)(ws + 0 * MB);
    bf16_t* Wt  = (bf16_t*)(ws + 8 * MB);   // [4][1024][1024] bf16: Q,K,V,O transposed
    bf16_t* Qm  = (bf16_t*)(ws + 16 * MB);  // [B,H,S,DH]
    bf16_t* Km  = (bf16_t*)(ws + 24 * MB);
    bf16_t* Vm  = (bf16_t*)(ws + 32 * MB);
    bf16_t* hid = (bf16_t*)(ws + 40 * MB);  // [B,S,D] bf16
    int* flag   = (int*)(ws + 48 * MB);

    convert_x_kernel<<<BDIM * SDIM * DDIM / (256 * 4), 256, 0, stream>>>(X, Xb, BDIM * SDIM * DDIM);
    transpose_w_kernel<<<dim3(32, 32, 4), 256, 0, stream>>>(WQ, WK, WV, WO, Wt);
    mask_flag_kernel<<<1, 256, 0, stream>>>(maskb, flag);
    // QKV projection: M=4096, N=3072 (Wt_Q|Wt_K|Wt_V contiguous)
    gemm_bt_kernel<0><<<dim3(32, 24), 256, 0, stream>>>(Xb, Wt, Qm, Km, Vm, nullptr);
    // attention: bh fastest for L2/L3 sharing of interaction lines across heads
    attn_kernel<<<dim3(BDIM * HDIM, SDIM / 64), 256, 0, stream>>>(Qm, Km, Vm, inter, maskb, flag, hid);
    // output projection: M=4096, N=1024
    gemm_bt_kernel<1><<<dim3(32, 8), 256, 0, stream>>>(hid, Wt + (size_t)3 * DDIM * DDIM,
                                                       nullptr, nullptr, nullptr, out);
}

// Round 2
// 569.964 us; speedup vs baseline: 1.3574x; 1.3574x over previous
//
#include <hip/hip_runtime.h>
#include <hip/hip_bf16.h>
#include <stdint.h>

#define BDIM 4
#define SDIM 1024
#define DDIM 1024
#define HDIM 16
#define DHDIM 64

typedef __bf16 bf16_t;
typedef __bf16 bf16x8 __attribute__((ext_vector_type(8)));
typedef __bf16 bf16x4 __attribute__((ext_vector_type(4)));
typedef float f32x4 __attribute__((ext_vector_type(4)));

typedef __attribute__((address_space(3))) uint32_t lds_u32;
typedef const __attribute__((address_space(1))) uint32_t glb_u32;

__device__ __forceinline__ void glds16(const void* g, void* l) {
    __builtin_amdgcn_global_load_lds((glb_u32*)g, (lds_u32*)l, 16, 0, 0);
}

// ---------------- conversions ----------------

__global__ __launch_bounds__(256) void convert_x_kernel(const float* __restrict__ X,
                                                        bf16_t* __restrict__ Xb, int n) {
    int i = (blockIdx.x * 256 + threadIdx.x) * 4;
    if (i >= n) return;
    float4 v = *(const float4*)(X + i);
    bf16x4 o;
    o[0] = (bf16_t)v.x; o[1] = (bf16_t)v.y; o[2] = (bf16_t)v.z; o[3] = (bf16_t)v.w;
    *(bf16x4*)(Xb + i) = o;
}

// W[k][n] fp32 -> Wt[n][k] bf16, for 4 weights (z selects)
__global__ __launch_bounds__(256) void transpose_w_kernel(const float* __restrict__ W0,
                                                          const float* __restrict__ W1,
                                                          const float* __restrict__ W2,
                                                          const float* __restrict__ W3,
                                                          bf16_t* __restrict__ Wt) {
    __shared__ float tile[32][33];
    int z = blockIdx.z;
    const float* W = (z == 0) ? W0 : (z == 1) ? W1 : (z == 2) ? W2 : W3;
    bf16_t* dst = Wt + (size_t)z * DDIM * DDIM;
    int bx = blockIdx.x * 32;  // n tile
    int by = blockIdx.y * 32;  // k tile
    int x = threadIdx.x & 31, y0 = threadIdx.x >> 5;
#pragma unroll
    for (int i = 0; i < 4; i++) {
        int y = y0 + i * 8;
        tile[y][x] = W[(size_t)(by + y) * DDIM + bx + x];
    }
    __syncthreads();
#pragma unroll
    for (int i = 0; i < 4; i++) {
        int y = y0 + i * 8;
        dst[(size_t)(bx + y) * DDIM + by + x] = (bf16_t)tile[x][y];
    }
}

// Detect mask element layout: uint8 bools -> bytes at i%4!=0 nonzero somewhere;
// int32 -> those bytes all 0. flag=1 means stride 1 (uint8), else stride 4.
__global__ __launch_bounds__(256) void mask_flag_kernel(const unsigned char* __restrict__ mb,
                                                        int* __restrict__ flag) {
    __shared__ int any;
    if (threadIdx.x == 0) any = 0;
    __syncthreads();
    int loc = 0;
    for (int i = threadIdx.x; i < BDIM * SDIM; i += 256)
        if ((i & 3) && mb[i]) loc = 1;
    if (loc) any = 1;
    __syncthreads();
    if (threadIdx.x == 0) *flag = any ? 1 : 0;
}

// ---------------- bias transpose + mask fuse ----------------
// inter[b][q][k][h] fp32 -> biasT[b*16+h][q][k] bf16, minus 1e9 where mask[b][k]==0
__global__ __launch_bounds__(256) void bias_tr_kernel(const float* __restrict__ inter,
                                                      const unsigned char* __restrict__ maskb,
                                                      const int* __restrict__ flagp,
                                                      bf16_t* __restrict__ biasT) {
    constexpr int QS = 72;            // q stride (bf16 elements)
    constexpr int HS = 16 * 72 + 8;   // h stride = 1160 (breaks pow2 banking)
    __shared__ bf16_t tile[16 * HS];  // ~37 KB
    __shared__ float pen[64];
    const int k0 = blockIdx.x * 64;
    const int q0 = blockIdx.y * 16;
    const int b  = blockIdx.z;
    const int t = threadIdx.x;
    const int mstride = (*flagp) ? 1 : 4;
    if (t < 64)
        pen[t] = maskb[((size_t)b * SDIM + k0 + t) * mstride] ? 0.f : 1.0e9f;

    // read 16 q-rows x (64 k x 16 h) floats, coalesced
    const float* src = inter + (((size_t)b * SDIM + q0) * SDIM + k0) * HDIM;
    const int k = t >> 2, h = (t & 3) * 4;   // within a row: rem = t*4 = k*16+h
#pragma unroll
    for (int q = 0; q < 16; q++) {
        float4 v = *(const float4*)(src + (size_t)q * SDIM * HDIM + t * 4);
        tile[(h + 0) * HS + q * QS + k] = (bf16_t)v.x;
        tile[(h + 1) * HS + q * QS + k] = (bf16_t)v.y;
        tile[(h + 2) * HS + q * QS + k] = (bf16_t)v.z;
        tile[(h + 3) * HS + q * QS + k] = (bf16_t)v.w;
    }
    __syncthreads();
    // write out: 256 rows (h,q) x 64 k bf16 (128 B rows, 8 lanes x 16 B)
#pragma unroll
    for (int p = 0; p < 8; p++) {
        int row = p * 32 + (t >> 3);
        int hh = row >> 4, qq = row & 15;
        int kc = (t & 7) * 8;
        bf16x8 vv = *(const bf16x8*)(tile + hh * HS + qq * QS + kc);
        bf16x8 ov;
#pragma unroll
        for (int u = 0; u < 8; u++) ov[u] = (bf16_t)((float)vv[u] - pen[kc + u]);
        *(bf16x8*)(biasT + ((size_t)(b * HDIM + hh) * SDIM + q0 + qq) * SDIM + k0 + kc) = ov;
    }
}

// ---------------- GEMM: C[m,n] = sum_k A[m,k] * Bt[n,k] (m97-style) ----------------
// MODE 0: write Q,K,V bf16 [B,H,S,DH] (Q scaled by 0.125), N=3072
// MODE 1: write fp32 C row-major [M,1024]
template <int MODE>
__global__ __launch_bounds__(256) void gemm_bt_kernel(const bf16_t* __restrict__ A,
                                                      const bf16_t* __restrict__ Bt,
                                                      bf16_t* __restrict__ Qo, bf16_t* __restrict__ Ko,
                                                      bf16_t* __restrict__ Vo, float* __restrict__ Co) {
    __shared__ bf16_t As[128 * 32];
    __shared__ bf16_t Bs[128 * 32];
    const int m0 = blockIdx.x * 128;
    const int n0 = blockIdx.y * 128;
    const int t = threadIdx.x;
    const int lane = t & 63, w = t >> 6;
    const int wm = w & 1, wn = w >> 1;
    const int low = lane & 15, quad = lane >> 4;
    f32x4 acc[4][4] = {};

    // global_load_lds: wave w stages rows [w*16, w*16+16); lds dest = base + lane*16B
    const int srow = w * 16 + (lane >> 2);
    const int koff = (lane & 3) * 8;
    const bf16_t* Ag = A + (size_t)(m0 + srow) * DDIM + koff;
    const bf16_t* Bg = Bt + (size_t)(n0 + srow) * DDIM + koff;
    bf16_t* AsW = As + w * 512;
    bf16_t* BsW = Bs + w * 512;

    for (int k0 = 0; k0 < DDIM; k0 += 32) {
        __syncthreads();
        glds16(Ag + k0, AsW);
        glds16(Ag + (size_t)64 * DDIM + k0, AsW + 64 * 32);
        glds16(Bg + k0, BsW);
        glds16(Bg + (size_t)64 * DDIM + k0, BsW + 64 * 32);
        __syncthreads();
        bf16x8 af[4], bv[4];
#pragma unroll
        for (int mt = 0; mt < 4; mt++)
            af[mt] = *(const bf16x8*)(As + (wm * 64 + mt * 16 + low) * 32 + quad * 8);
#pragma unroll
        for (int nt = 0; nt < 4; nt++)
            bv[nt] = *(const bf16x8*)(Bs + (wn * 64 + nt * 16 + low) * 32 + quad * 8);
#pragma unroll
        for (int mt = 0; mt < 4; mt++)
#pragma unroll
            for (int nt = 0; nt < 4; nt++)
                acc[mt][nt] = __builtin_amdgcn_mfma_f32_16x16x32_bf16(af[mt], bv[nt], acc[mt][nt], 0, 0, 0);
    }

#pragma unroll
    for (int mt = 0; mt < 4; mt++) {
#pragma unroll
        for (int nt = 0; nt < 4; nt++) {
#pragma unroll
            for (int r = 0; r < 4; r++) {
                int mrow = m0 + wm * 64 + mt * 16 + quad * 4 + r;
                int ncol = n0 + wn * 64 + nt * 16 + low;
                float vv = acc[mt][nt][r];
                if (MODE == 0) {
                    int which = ncol >> 10, nl = ncol & 1023;
                    int h = nl >> 6, dh = nl & 63;
                    int b = mrow >> 10, s = mrow & 1023;
                    size_t idx = ((size_t)(b * HDIM + h) * SDIM + s) * DHDIM + dh;
                    if (which == 0) Qo[idx] = (bf16_t)(vv * 0.125f);
                    else if (which == 1) Ko[idx] = (bf16_t)vv;
                    else Vo[idx] = (bf16_t)vv;
                } else {
                    Co[(size_t)mrow * DDIM + ncol] = vv;
                }
            }
        }
    }
}

// ---------------- fused attention ----------------
// grid: (B*H, S/64); block 256 (4 waves); wave w owns q rows [q0+16w, q0+16w+16)
__global__ __launch_bounds__(256) void attn_kernel(const bf16_t* __restrict__ Q,
                                                   const bf16_t* __restrict__ K,
                                                   const bf16_t* __restrict__ V,
                                                   const bf16_t* __restrict__ biasT,
                                                   bf16_t* __restrict__ hid) {
    __shared__ bf16_t Vt[64 * 72];   // V^T tile: [dh][key], padded stride 72
    __shared__ bf16_t P[4][16 * 72]; // per-wave P tile, padded stride 72
    const int bh = blockIdx.x;
    const int b = bh >> 4, h = bh & 15;
    const int q0 = blockIdx.y * 64;
    const int t = threadIdx.x;
    const int w = t >> 6, lane = t & 63;
    const int low = lane & 15, quad = lane >> 4;

    const bf16_t* Qb = Q + (size_t)bh * SDIM * DHDIM;
    const bf16_t* Kb = K + (size_t)bh * SDIM * DHDIM;
    const bf16_t* Vb = V + (size_t)bh * SDIM * DHDIM;
    const bf16_t* biasB = biasT + (size_t)bh * SDIM * SDIM;

    const int qrow = q0 + w * 16 + low;  // A-operand row (q)
    bf16x8 qf0 = *(const bf16x8*)(Qb + (size_t)qrow * DHDIM + quad * 8);
    bf16x8 qf1 = *(const bf16x8*)(Qb + (size_t)qrow * DHDIM + 32 + quad * 8);

    const int qr = q0 + w * 16 + quad * 4;  // C-layout row base

    float mrow[4], lrow[4];
    f32x4 accO[4] = {};
#pragma unroll
    for (int r = 0; r < 4; r++) { mrow[r] = -3.0e38f; lrow[r] = 0.f; }

    for (int kt = 0; kt < SDIM / 64; kt++) {
        const int kbase = kt * 64;
        __syncthreads();  // prior-iteration Vt/P reads complete
        // stage V^T: 512 chunks of 8 bf16
        {
            int c0 = t, c1 = t + 256;
            int key0 = c0 >> 3, d0 = (c0 & 7) * 8;
            int key1 = c1 >> 3, d1 = (c1 & 7) * 8;
            bf16x8 v0 = *(const bf16x8*)(Vb + (size_t)(kbase + key0) * DHDIM + d0);
            bf16x8 v1 = *(const bf16x8*)(Vb + (size_t)(kbase + key1) * DHDIM + d1);
#pragma unroll
            for (int u = 0; u < 8; u++) Vt[(d0 + u) * 72 + key0] = v0[u];
#pragma unroll
            for (int u = 0; u < 8; u++) Vt[(d1 + u) * 72 + key1] = v1[u];
        }
        // S = Q K^T (Q pre-scaled by 0.125)
        f32x4 sacc[4];
#pragma unroll
        for (int nt = 0; nt < 4; nt++) {
            int krow = kbase + nt * 16 + low;
            bf16x8 kf0 = *(const bf16x8*)(Kb + (size_t)krow * DHDIM + quad * 8);
            bf16x8 kf1 = *(const bf16x8*)(Kb + (size_t)krow * DHDIM + 32 + quad * 8);
            f32x4 z = {};
            z = __builtin_amdgcn_mfma_f32_16x16x32_bf16(qf0, kf0, z, 0, 0, 0);
            z = __builtin_amdgcn_mfma_f32_16x16x32_bf16(qf1, kf1, z, 0, 0, 0);
            sacc[nt] = z;
        }
        __syncthreads();  // Vt ready
        // bias (mask already folded in)
        float sv[4][4];
#pragma unroll
        for (int nt = 0; nt < 4; nt++) {
            int kk = kbase + nt * 16 + low;
#pragma unroll
            for (int r = 0; r < 4; r++) {
                float biasv = (float)biasB[(size_t)(qr + r) * SDIM + kk];
                sv[nt][r] = sacc[nt][r] + biasv;
            }
        }
        // online softmax update (rows live in a 16-lane quad)
#pragma unroll
        for (int r = 0; r < 4; r++) {
            float vmx = fmaxf(fmaxf(sv[0][r], sv[1][r]), fmaxf(sv[2][r], sv[3][r]));
            vmx = fmaxf(vmx, __shfl_xor(vmx, 1));
            vmx = fmaxf(vmx, __shfl_xor(vmx, 2));
            vmx = fmaxf(vmx, __shfl_xor(vmx, 4));
            vmx = fmaxf(vmx, __shfl_xor(vmx, 8));
            float mn = fmaxf(mrow[r], vmx);
            float alpha = __expf(mrow[r] - mn);
            mrow[r] = mn;
            lrow[r] *= alpha;
#pragma unroll
            for (int nt = 0; nt < 4; nt++) accO[nt][r] *= alpha;
            float rs = 0.f;
#pragma unroll
            for (int nt = 0; nt < 4; nt++) {
                float p = __expf(sv[nt][r] - mn);
                sv[nt][r] = p;
                rs += p;
            }
            rs += __shfl_xor(rs, 1);
            rs += __shfl_xor(rs, 2);
            rs += __shfl_xor(rs, 4);
            rs += __shfl_xor(rs, 8);
            lrow[r] += rs;
        }
        // P (C-layout) -> LDS (A-layout readable)
        bf16_t* Pw = &P[w][0];
#pragma unroll
        for (int nt = 0; nt < 4; nt++)
#pragma unroll
            for (int r = 0; r < 4; r++)
                Pw[(quad * 4 + r) * 72 + nt * 16 + low] = (bf16_t)sv[nt][r];
        __syncthreads();
        // O += P V
#pragma unroll
        for (int step = 0; step < 2; step++) {
            bf16x8 pf = *(const bf16x8*)(Pw + low * 72 + step * 32 + quad * 8);
#pragma unroll
            for (int nt = 0; nt < 4; nt++) {
                bf16x8 vf = *(const bf16x8*)(Vt + (nt * 16 + low) * 72 + step * 32 + quad * 8);
                accO[nt] = __builtin_amdgcn_mfma_f32_16x16x32_bf16(pf, vf, accO[nt], 0, 0, 0);
            }
        }
    }
    // epilogue: hidden[b, q, h*64+dh] bf16
#pragma unroll
    for (int r = 0; r < 4; r++) {
        float inv = 1.f / lrow[r];
#pragma unroll
        for (int nt = 0; nt < 4; nt++) {
            hid[((size_t)b * SDIM + (qr + r)) * DDIM + h * 64 + nt * 16 + low] =
                (bf16_t)(accO[nt][r] * inv);
        }
    }
}

// ---------------- launcher ----------------

extern "C" void kernel_launch(void* const* d_in, const int* in_sizes, int n_in,
                              void* d_out, int out_size, void* d_ws, size_t ws_size,
                              hipStream_t stream) {
    const float* X = (const float*)d_in[0];
    const unsigned char* maskb = (const unsigned char*)d_in[1];
    const float* inter = (const float*)d_in[2];
    const float* WQ = (const float*)d_in[3];
    const float* WK = (const float*)d_in[4];
    const float* WV = (const float*)d_in[5];
    const float* WO = (const float*)d_in[6];
    float* out = (float*)d_out;

    char* ws = (char*)d_ws;
    const size_t MB = 1024 * 1024;
    bf16_t* Xb    = (bf16_t*)(ws + 0 * MB);
    bf16_t* Wt    = (bf16_t*)(ws + 8 * MB);    // [4][1024][1024] bf16 transposed
    bf16_t* Qm    = (bf16_t*)(ws + 16 * MB);   // [B,H,S,DH]
    bf16_t* Km    = (bf16_t*)(ws + 24 * MB);
    bf16_t* Vm    = (bf16_t*)(ws + 32 * MB);
    bf16_t* hid   = (bf16_t*)(ws + 40 * MB);   // [B,S,D] bf16
    int* flag     = (int*)(ws + 48 * MB);
    bf16_t* biasT = (bf16_t*)(ws + 64 * MB);   // [B*H][S][S] bf16, 128 MB

    convert_x_kernel<<<BDIM * SDIM * DDIM / (256 * 4), 256, 0, stream>>>(X, Xb, BDIM * SDIM * DDIM);
    transpose_w_kernel<<<dim3(32, 32, 4), 256, 0, stream>>>(WQ, WK, WV, WO, Wt);
    mask_flag_kernel<<<1, 256, 0, stream>>>(maskb, flag);
    bias_tr_kernel<<<dim3(16, 64, 4), 256, 0, stream>>>(inter, maskb, flag, biasT);
    // QKV projection: M=4096, N=3072 (Wt_Q|Wt_K|Wt_V contiguous)
    gemm_bt_kernel<0><<<dim3(32, 24), 256, 0, stream>>>(Xb, Wt, Qm, Km, Vm, nullptr);
    attn_kernel<<<dim3(BDIM * HDIM, SDIM / 64), 256, 0, stream>>>(Qm, Km, Vm, biasT, hid);
    // output projection: M=4096, N=1024
    gemm_bt_kernel<1><<<dim3(32, 8), 256, 0, stream>>>(hid, Wt + (size_t)3 * DDIM * DDIM,
                                                       nullptr, nullptr, nullptr, out);
}